// Round 1
// 389.911 us; speedup vs baseline: 1.0382x; 1.0382x over previous
//
#include <hip/hip_runtime.h>
#include <hip/hip_bf16.h>
#include <math.h>

#define NNODES 100000
#define NEDGES 20000
#define NNZ_   2000000
#define FDIM   128
#define BN_EPS 1e-5f

// ---- bucket-sort geometry ----
#define NBUCK 256
#define CAP   9216        // per-bucket capacity (mean ~7812, sigma ~88 -> +16 sigma)
#define BPB_E 79          // bins/bucket, edge dir
#define BPB_N 391         // bins/bucket, node dir
#define SH_E  17          // edge entry = (e<<17)|n
#define SH_N  15          // node entry = (n<<15)|e

typedef __attribute__((ext_vector_type(8))) short bf16x8_t;
typedef __attribute__((ext_vector_type(4))) float f32x4_t;
typedef __attribute__((ext_vector_type(8))) unsigned short u16x8_t;

__device__ __forceinline__ float sigmoidf_(float x) {
    return 1.0f / (1.0f + __expf(-x));
}
__device__ __forceinline__ float bf2f(unsigned short u) {
    return __uint_as_float(((unsigned)u) << 16);
}
__device__ __forceinline__ unsigned short f2bf(float f) {
    __hip_bfloat16 h = __float2bfloat16(f);   // RNE
    return *reinterpret_cast<unsigned short*>(&h);
}

// ---- prep: bf16 copy of W_nh (B-operand layout = as-is) + transpose W_en ----
__global__ __launch_bounds__(256) void prep_w(
    const float* __restrict__ W_nh, const float* __restrict__ W_en,
    unsigned short* __restrict__ Wnh_bf, float* __restrict__ WTen)
{
    int idx = blockIdx.x * blockDim.x + threadIdx.x;
    if (idx < FDIM * FDIM) {
        Wnh_bf[idx] = f2bf(W_nh[idx]);
    } else {
        int j = idx - FDIM * FDIM;
        if (j >= 2 * FDIM * FDIM) return;
        int k = j >> 7, c = j & 127;
        WTen[j] = W_en[c * 2 * FDIM + k];
    }
}

// ---- GEMM1 via MFMA: out[100000,128] = sigmoid(x0 @ W_nh^T + b), bf16 out ----
// block: 32 rows x 128 cols; 4 waves: wave&1 -> m-half(16), wave>>1 -> n-half(64)
__global__ __launch_bounds__(256) void gemm1_mfma(
    const float* __restrict__ x0, const unsigned short* __restrict__ Wb,
    const float* __restrict__ bias, unsigned short* __restrict__ out)
{
    __shared__ unsigned short As[32][FDIM + 8];   // +8 shorts: kills bank conflicts, keeps 16B align
    const int tid  = threadIdx.x;
    const int row0 = blockIdx.x * 32;
    // stage x0 tile -> bf16 LDS (each thread: 16 elems = 4 float4 loads)
    {
        int r = tid >> 3, c0 = (tid & 7) * 16;
        const float* src = x0 + (size_t)(row0 + r) * FDIM + c0;
        unsigned short* dst = &As[r][c0];
        #pragma unroll
        for (int i = 0; i < 4; i++) {
            float4 v = *(const float4*)(src + i * 4);
            dst[i * 4 + 0] = f2bf(v.x);
            dst[i * 4 + 1] = f2bf(v.y);
            dst[i * 4 + 2] = f2bf(v.z);
            dst[i * 4 + 3] = f2bf(v.w);
        }
    }
    __syncthreads();
    const int wave  = tid >> 6;
    const int lane  = tid & 63;
    const int mhalf = wave & 1;
    const int nhalf = wave >> 1;
    const int lm    = lane & 15;
    const int quad  = lane >> 4;
    f32x4_t acc[4] = {};
    #pragma unroll
    for (int ks = 0; ks < 4; ks++) {
        bf16x8_t a = *(const bf16x8_t*)&As[mhalf * 16 + lm][ks * 32 + quad * 8];
        #pragma unroll
        for (int nt = 0; nt < 4; nt++) {
            int n = nhalf * 64 + nt * 16 + lm;
            bf16x8_t b = *(const bf16x8_t*)(Wb + (size_t)n * FDIM + ks * 32 + quad * 8);
            acc[nt] = __builtin_amdgcn_mfma_f32_16x16x32_bf16(a, b, acc[nt], 0, 0, 0);
        }
    }
    // D layout: col(n)=lane&15, row(m)=quad*4+reg
    const int mbase = row0 + mhalf * 16 + quad * 4;
    #pragma unroll
    for (int nt = 0; nt < 4; nt++) {
        int n = nhalf * 64 + nt * 16 + lm;
        float bv = bias[n];
        #pragma unroll
        for (int r2 = 0; r2 < 4; r2++) {
            out[(size_t)(mbase + r2) * FDIM + n] = f2bf(sigmoidf_(acc[nt][r2] + bv));
        }
    }
}

// ---- GEMM2 (fp32 vector): out[20000,128] = sigmoid(cat(x1,B) @ W_en^T + b), bf16 out ----
__global__ __launch_bounds__(256, 2) void gemm_sig_bf16(
    const float* __restrict__ A1, const float* __restrict__ A2,
    const float* __restrict__ WT, const float* __restrict__ bias,
    unsigned short* __restrict__ out)
{
    constexpr int K = 256, BK = 64;
    __shared__ float As[32][BK + 4];
    __shared__ float Ws[BK][FDIM];
    const int tid  = threadIdx.x;
    const int row0 = blockIdx.x * 32;
    const int tcol = tid & 31;
    const int trow = tid >> 5;
    float acc[4][4] = {};
    for (int kk = 0; kk < K; kk += BK) {
        const float* Asrc = (kk < FDIM) ? A1 : A2;
        const int koff    = (kk < FDIM) ? kk : kk - FDIM;
        #pragma unroll
        for (int i = 0; i < 2; i++) {
            int l = tid + i * 256;
            int r = l >> 4, j = l & 15;
            float4 v = *(const float4*)(Asrc + (size_t)(row0 + r) * FDIM + koff + j * 4);
            *(float4*)&As[r][j * 4] = v;
        }
        #pragma unroll
        for (int i = 0; i < 8; i++) {
            int l = tid + i * 256;
            int k = l >> 5, j = l & 31;
            float4 v = *(const float4*)(WT + (size_t)(kk + k) * FDIM + j * 4);
            *(float4*)&Ws[k][j * 4] = v;
        }
        __syncthreads();
        #pragma unroll
        for (int k = 0; k < BK; k += 4) {
            float4 a[4];
            #pragma unroll
            for (int r = 0; r < 4; r++)
                a[r] = *(const float4*)&As[trow * 4 + r][k];
            #pragma unroll
            for (int kq = 0; kq < 4; kq++) {
                float4 w = *(const float4*)&Ws[k + kq][tcol * 4];
                #pragma unroll
                for (int r = 0; r < 4; r++) {
                    float av = (kq == 0) ? a[r].x : (kq == 1) ? a[r].y
                             : (kq == 2) ? a[r].z : a[r].w;
                    acc[r][0] += av * w.x;
                    acc[r][1] += av * w.y;
                    acc[r][2] += av * w.z;
                    acc[r][3] += av * w.w;
                }
            }
        }
        __syncthreads();
    }
    float4 bv = *(const float4*)(bias + tcol * 4);
    #pragma unroll
    for (int r = 0; r < 4; r++) {
        int row = row0 + trow * 4 + r;
        ushort4 o;
        o.x = f2bf(sigmoidf_(acc[r][0] + bv.x));
        o.y = f2bf(sigmoidf_(acc[r][1] + bv.y));
        o.z = f2bf(sigmoidf_(acc[r][2] + bv.z));
        o.w = f2bf(sigmoidf_(acc[r][3] + bv.w));
        *(ushort4*)(out + (size_t)row * FDIM + tcol * 4) = o;
    }
}

// ---- Pass A: coarse bucket partition (both directions in one pass) ----
__global__ __launch_bounds__(1024) void bucket_scatter(
    const int* __restrict__ ni, const int* __restrict__ ei,
    unsigned* __restrict__ buck_e, unsigned* __restrict__ buck_n,
    int* __restrict__ gcur_e, int* __restrict__ gcur_n)
{
    __shared__ int lh_e[NBUCK], lh_n[NBUCK], lb_e[NBUCK], lb_n[NBUCK];
    const int t = threadIdx.x;
    if (t < NBUCK) { lh_e[t] = 0; lh_n[t] = 0; }
    __syncthreads();
    unsigned ent_e[4], ent_n[4];
    int be[4], bn[4], re[4], rn[4];
    const int base = blockIdx.x * 4096;
    #pragma unroll
    for (int j = 0; j < 4; j++) {
        int i = base + j * 1024 + t;
        if (i < NNZ_) {
            unsigned n = (unsigned)ni[i], e = (unsigned)ei[i];
            ent_e[j] = (e << SH_E) | n;  be[j] = (int)(e / BPB_E);
            ent_n[j] = (n << SH_N) | e;  bn[j] = (int)(n / BPB_N);
            re[j] = atomicAdd(&lh_e[be[j]], 1);
            rn[j] = atomicAdd(&lh_n[bn[j]], 1);
        } else { be[j] = -1; }
    }
    __syncthreads();
    if (t < NBUCK) {
        lb_e[t] = t * CAP + atomicAdd(&gcur_e[t], lh_e[t]);
        lb_n[t] = t * CAP + atomicAdd(&gcur_n[t], lh_n[t]);
    }
    __syncthreads();
    #pragma unroll
    for (int j = 0; j < 4; j++) {
        if (be[j] >= 0) {
            buck_e[(size_t)lb_e[be[j]] + re[j]] = ent_e[j];
            buck_n[(size_t)lb_n[bn[j]] + rn[j]] = ent_n[j];
        }
    }
}

// ---- Pass B: sort one bucket into its compact region (bases inline) ----
template<int BPB, int SH, unsigned MASK, int NBINS, typename OUT>
__device__ __forceinline__ void sort_bucket(
    const unsigned* __restrict__ region, int cnt, int gbase, int b0,
    OUT* __restrict__ csr, int* __restrict__ off)
{
    __shared__ unsigned lh[512];
    __shared__ unsigned lw[4];
    const int t = threadIdx.x;
    lh[t] = 0; lh[t + 256] = 0;
    __syncthreads();
    for (int i = t; i < cnt; i += 256) {
        int bin = (int)(region[i] >> SH) - b0;
        atomicAdd(&lh[bin], 1u);
    }
    __syncthreads();
    unsigned h0 = lh[2 * t], h1 = lh[2 * t + 1];
    unsigned s = h0 + h1, inc = s;
    const int lane = t & 63;
    #pragma unroll
    for (int d = 1; d <= 32; d <<= 1) {
        unsigned v = (unsigned)__shfl_up((int)inc, d, 64);
        if (lane >= d) inc += v;
    }
    if (lane == 63) lw[t >> 6] = inc;
    __syncthreads();
    unsigned pre = 0;
    #pragma unroll
    for (int w = 0; w < 4; w++) if (w < (t >> 6)) pre += lw[w];
    unsigned excl = pre + inc - s;
    unsigned c0 = (unsigned)gbase + excl;
    unsigned c1 = c0 + h0;
    lh[2 * t] = c0; lh[2 * t + 1] = c1;
    int i0 = 2 * t, i1 = 2 * t + 1;
    if (i0 <= BPB && b0 + i0 <= NBINS) off[b0 + i0] = (int)c0;
    if (i1 <= BPB && b0 + i1 <= NBINS) off[b0 + i1] = (int)c1;
    __syncthreads();
    for (int i = t; i < cnt; i += 256) {
        unsigned ent = region[i];
        int bin = (int)(ent >> SH) - b0;
        unsigned pos = atomicAdd(&lh[bin], 1u);
        csr[pos] = (OUT)(ent & MASK);
    }
}

__global__ __launch_bounds__(256) void bucket_sort(
    const unsigned* __restrict__ buck_e, const unsigned* __restrict__ buck_n,
    const int* __restrict__ gcur_e, const int* __restrict__ gcur_n,
    unsigned* __restrict__ csr_e, unsigned short* __restrict__ csr_n,
    int* __restrict__ off_e, int* __restrict__ off_n)
{
    const int b = blockIdx.x & 255;
    const int* gc = (blockIdx.x < 256) ? gcur_e : gcur_n;
    __shared__ int ws4[4];
    const int t = threadIdx.x;
    int v = (t < b) ? gc[t] : 0;
    #pragma unroll
    for (int d = 32; d > 0; d >>= 1) v += __shfl_down(v, d, 64);
    if ((t & 63) == 0) ws4[t >> 6] = v;
    __syncthreads();
    const int gbase = ws4[0] + ws4[1] + ws4[2] + ws4[3];
    const int cnt = gc[b];
    __syncthreads();
    if (blockIdx.x < 256)
        sort_bucket<BPB_E, SH_E, 0x1FFFFu, NEDGES, unsigned>(
            buck_e + (size_t)b * CAP, cnt, gbase, b * BPB_E, csr_e, off_e);
    else
        sort_bucket<BPB_N, SH_N, 0x7FFFu, NNODES, unsigned short>(
            buck_n + (size_t)b * CAP, cnt, gbase, b * BPB_N, csr_n, off_n);
}

// ---- segmented sum v2: one wave per segment, 16B gathers, deep ILP ----
// lane = (sub<<4)|c : c = col-group (8 bf16 cols = 16B), sub = row phase (0..3).
// Main loop keeps U dwordx4 gathers in flight (4*U rows per iteration).
// Cross-sub reduction via 2x shfl_xor at the end; fused BN+sigmoid finalize.
template<typename IDX, int U>
__global__ __launch_bounds__(256) void seg_sum_fin_v2(
    const unsigned short* __restrict__ table, const IDX* __restrict__ csr,
    const int* __restrict__ off, const float* __restrict__ x,
    const float* __restrict__ g, const float* __restrict__ bb,
    const float* __restrict__ mm, const float* __restrict__ vv,
    float* __restrict__ agg_out, float* __restrict__ fin_out, int nseg)
{
    const int seg = blockIdx.x * 4 + (threadIdx.x >> 6);
    if (seg >= nseg) return;
    const int lane = threadIdx.x & 63;
    const int c    = lane & 15;
    const int sub  = lane >> 4;
    const int c8   = c * 8;

    const int i0 = off[seg], i1 = off[seg + 1];
    f32x4_t a0 = {}, a1 = {};

    int i = i0;
    // main loop: 4*U rows per iteration, U gathers in flight per lane
    for (; i + 4 * U <= i1; i += 4 * U) {
        int r[U];
        u16x8_t v[U];
        #pragma unroll
        for (int u = 0; u < U; u++) r[u] = (int)csr[i + 4 * u + sub];
        #pragma unroll
        for (int u = 0; u < U; u++)
            v[u] = *(const u16x8_t*)(table + (size_t)r[u] * FDIM + c8);
        #pragma unroll
        for (int u = 0; u < U; u++) {
            a0[0] += bf2f(v[u][0]); a0[1] += bf2f(v[u][1]);
            a0[2] += bf2f(v[u][2]); a0[3] += bf2f(v[u][3]);
            a1[0] += bf2f(v[u][4]); a1[1] += bf2f(v[u][5]);
            a1[2] += bf2f(v[u][6]); a1[3] += bf2f(v[u][7]);
        }
    }
    // remainder: up to 4*U-1 rows, predicated loads issued in parallel
    if (i < i1) {
        u16x8_t v[U];
        #pragma unroll
        for (int u = 0; u < U; u++) {
            int row = i + 4 * u + sub;
            u16x8_t z = 0;
            v[u] = z;
            if (row < i1)
                v[u] = *(const u16x8_t*)(table + (size_t)csr[row] * FDIM + c8);
        }
        #pragma unroll
        for (int u = 0; u < U; u++) {
            a0[0] += bf2f(v[u][0]); a0[1] += bf2f(v[u][1]);
            a0[2] += bf2f(v[u][2]); a0[3] += bf2f(v[u][3]);
            a1[0] += bf2f(v[u][4]); a1[1] += bf2f(v[u][5]);
            a1[2] += bf2f(v[u][6]); a1[3] += bf2f(v[u][7]);
        }
    }

    // reduce across sub (lane bits 4,5)
    #pragma unroll
    for (int j = 0; j < 4; j++) {
        a0[j] += __shfl_xor(a0[j], 16, 64);
        a0[j] += __shfl_xor(a0[j], 32, 64);
        a1[j] += __shfl_xor(a1[j], 16, 64);
        a1[j] += __shfl_xor(a1[j], 32, 64);
    }

    // finalize: lanes sub<2 each own one float4 (cols c*8 + sub*4 .. +4)
    if (sub < 2) {
        const int q = c8 + sub * 4;
        f32x4_t s = sub ? a1 : a0;
        if (agg_out)
            *(f32x4_t*)(agg_out + (size_t)seg * FDIM + q) = s;
        if (fin_out) {
            f32x4_t xv = *(const f32x4_t*)(x + (size_t)seg * FDIM + q);
            f32x4_t gg = *(const f32x4_t*)(g + q);
            f32x4_t bt = *(const f32x4_t*)(bb + q);
            f32x4_t mn = *(const f32x4_t*)(mm + q);
            f32x4_t vr = *(const f32x4_t*)(vv + q);
            f32x4_t o;
            #pragma unroll
            for (int j = 0; j < 4; j++)
                o[j] = sigmoidf_((xv[j] - mn[j]) * (gg[j] * rsqrtf(vr[j] + BN_EPS))
                                 + bt[j] + s[j]);
            *(f32x4_t*)(fin_out + (size_t)seg * FDIM + q) = o;
        }
    }
}

extern "C" void kernel_launch(void* const* d_in, const int* in_sizes, int n_in,
                              void* d_out, int out_size, void* d_ws, size_t ws_size,
                              hipStream_t stream)
{
    const float* x0       = (const float*)d_in[0];
    const float* x1       = (const float*)d_in[1];
    const int*   node_idx = (const int*)d_in[2];
    const int*   edge_idx = (const int*)d_in[3];
    const float* W_nh     = (const float*)d_in[4];
    const float* b_nh     = (const float*)d_in[5];
    const float* W_en     = (const float*)d_in[6];
    const float* b_en     = (const float*)d_in[7];
    const float* bn0g = (const float*)d_in[8];
    const float* bn0b = (const float*)d_in[9];
    const float* bn0m = (const float*)d_in[10];
    const float* bn0v = (const float*)d_in[11];
    const float* bn1g = (const float*)d_in[12];
    const float* bn1b = (const float*)d_in[13];
    const float* bn1m = (const float*)d_in[14];
    const float* bn1v = (const float*)d_in[15];

    float* ws = (float*)d_ws;
    float* B    = ws;                           // node_msg_agg fp32 [20000,128]
    float* WTen = B + (size_t)NEDGES * FDIM;    // [256,128] fp32
    unsigned short* Wnh_bf = (unsigned short*)(WTen + 2 * FDIM * FDIM); // [128,128] bf16
    unsigned short* A_bf = Wnh_bf + FDIM * FDIM;                  // [100000,128] bf16
    unsigned short* D_bf = A_bf + (size_t)NNODES * FDIM;          // [20000,128] bf16
    int* ip    = (int*)(D_bf + (size_t)NEDGES * FDIM);
    int* off_e = ip;                    // 20001 (pad 20004)
    int* off_n = off_e + 20004;         // 100001 (pad 100004)
    unsigned* csr_e = (unsigned*)(off_n + 100004);          // 2M u32
    unsigned short* csr_n = (unsigned short*)(csr_e + NNZ_);// 2M u16
    unsigned* buck_e = (unsigned*)(csr_n + NNZ_);           // [NBUCK*CAP]
    unsigned* buck_n = buck_e + (size_t)NBUCK * CAP;        // [NBUCK*CAP]
    int* gcur_e = (int*)(buck_n + (size_t)NBUCK * CAP);     // 256
    int* gcur_n = gcur_e + NBUCK;                           // 256

    // --- CSR build via 2-level bucket sort ---
    hipMemsetAsync(gcur_e, 0, 2 * NBUCK * sizeof(int), stream);
    bucket_scatter<<<(NNZ_ + 4095) / 4096, 1024, 0, stream>>>(
        node_idx, edge_idx, buck_e, buck_n, gcur_e, gcur_n);
    bucket_sort<<<2 * NBUCK, 256, 0, stream>>>(buck_e, buck_n, gcur_e, gcur_n,
                                               csr_e, csr_n, off_e, off_n);

    prep_w<<<(3 * FDIM * FDIM + 255) / 256, 256, 0, stream>>>(W_nh, W_en, Wnh_bf, WTen);

    float* out0 = (float*)d_out;
    float* out1 = out0 + (size_t)NNODES * FDIM;

    // node -> hyperedge: GEMM1 (MFMA, bf16 out) then pull-aggregate (+ fused x1_out)
    gemm1_mfma<<<NNODES / 32, 256, 0, stream>>>(x0, Wnh_bf, b_nh, A_bf);
    seg_sum_fin_v2<unsigned, 8><<<(NEDGES + 3) / 4, 256, 0, stream>>>(
        A_bf, csr_e, off_e, x1, bn1g, bn1b, bn1m, bn1v, B, out1, NEDGES);

    // hyperedge -> node: GEMM2 (fp32 vector, bf16 out) then pull-aggregate (+ fused x0_out)
    gemm_sig_bf16<<<NEDGES / 32, 256, 0, stream>>>(x1, B, WTen, b_en, D_bf);
    seg_sum_fin_v2<unsigned short, 4><<<(NNODES + 3) / 4, 256, 0, stream>>>(
        D_bf, csr_n, off_n, x0, bn0g, bn0b, bn0m, bn0v, nullptr, out0, NNODES);
}